// Round 1
// baseline (228.912 us; speedup 1.0000x reference)
//
#include <hip/hip_runtime.h>

#define HH 512
#define WW 512
#define BATCH 16
#define TW 32
#define TH 8
#define LW (TW + 4)   // 36
#define LH (TH + 2)   // 10

// 12 unique offsets (each appears twice in the reference with flipped sign,
// giving identical contributions since di is squared and do is abs'd).
__device__ __constant__ int c_dummy; // (unused, keeps section non-empty)

__launch_bounds__(256)
__global__ void smooth_loss_kernel(const float* __restrict__ x,
                                   const float* __restrict__ outp,
                                   float* __restrict__ total) {
    __shared__ float s_y[3][LH][LW];
    __shared__ float s_o[3][LH][LW];

    const int b  = blockIdx.z;
    const int h0 = blockIdx.y * TH;
    const int w0 = blockIdx.x * TW;
    const int tx = threadIdx.x;
    const int ty = threadIdx.y;
    const int tid = ty * TW + tx;

    // ---- stage ycc + output tile (with halo: rows [h0, h0+TH+2), cols [w0-2, w0+TW+2)) ----
    for (int i = tid; i < 3 * LH * LW; i += 256) {
        const int c   = i / (LH * LW);
        const int rem = i % (LH * LW);
        const int r   = rem / LW;
        const int cc  = rem % LW;
        const int h   = h0 + r;
        const int w   = w0 + cc - 2;
        float yv = 0.f, ov = 0.f;
        if (h < HH && w >= 0 && w < WW) {
            const int flat = (((b * 3 + c) * HH + h) * WW + w);
            const int j    = flat % 3;          // column of the 3x3 matrix
            const int g0   = flat - j;          // group base (flat memory, groups of 3)
            const float x0 = x[g0];
            const float x1 = x[g0 + 1];
            const float x2 = x[g0 + 2];
            // mat columns (faithful to reference's reshape(-1,3) @ mat + bias)
            const float a0 = (j == 0) ? 0.257f : ((j == 1) ? -0.148f : 0.439f);
            const float a1 = (j == 0) ? 0.564f : ((j == 1) ? -0.291f : -0.368f);
            const float a2 = (j == 0) ? 0.098f : ((j == 1) ?  0.439f : -0.071f);
            const float bb = (j == 0) ? (16.f / 255.f) : (128.f / 255.f);
            yv = fmaf(x0, a0, fmaf(x1, a1, fmaf(x2, a2, bb)));
            ov = outp[flat];
        }
        s_y[c][r][cc] = yv;
        s_o[c][r][cc] = ov;
    }
    __syncthreads();

    // ---- compute 12 unique stencil-pair contributions for this thread's pixel ----
    const int h = h0 + ty;   // always < HH (grid exactly tiles the image)
    const int w = w0 + tx;

    const float by0 = s_y[0][ty][tx + 2];
    const float by1 = s_y[1][ty][tx + 2];
    const float by2 = s_y[2][ty][tx + 2];
    const float bo0 = s_o[0][ty][tx + 2];
    const float bo1 = s_o[1][ty][tx + 2];
    const float bo2 = s_o[2][ty][tx + 2];

    constexpr int DYs[12] = {1, 0, 1,  1, 2, 0, 2,  2, 1,  1, 2,  2};
    constexpr int DXs[12] = {0, 1, 1, -1, 0, 2, 1, -1, 2, -2, 2, -2};
    constexpr float SC = -1.f / 200.f;   // -1/(2*sigma^2), sigma=10

    float acc = 0.f;
#pragma unroll
    for (int k = 0; k < 12; ++k) {
        const int dy = DYs[k];
        const int dx = DXs[k];
        const int adx = (dx < 0) ? -dx : dx;
        // 2x: each unique offset appears twice in the reference's 24-offset list
        const float inv_norm =
            2.0f / ((float)BATCH * (float)(HH - dy) * (float)(WW - adx));
        const int hp = h + dy;
        const int wp = w + dx;
        if (hp < HH && wp >= 0 && wp < WW) {
            const int r  = ty + dy;
            const int cc = tx + 2 + dx;
            const float d0 = s_y[0][r][cc] - by0;
            const float d1 = s_y[1][r][cc] - by1;
            const float d2 = s_y[2][r][cc] - by2;
            const float sad = fabsf(s_o[0][r][cc] - bo0)
                            + fabsf(s_o[1][r][cc] - bo1)
                            + fabsf(s_o[2][r][cc] - bo2);
            const float wgt = __expf(SC * (d0 * d0 + d1 * d1 + d2 * d2));
            acc += inv_norm * wgt * sad;
        }
    }

    // ---- block reduction: wave shuffle, then cross-wave via LDS, one atomic ----
#pragma unroll
    for (int off = 32; off > 0; off >>= 1)
        acc += __shfl_down(acc, off, 64);

    __shared__ float s_part[4];
    const int lane = tid & 63;
    const int wid  = tid >> 6;
    if (lane == 0) s_part[wid] = acc;
    __syncthreads();
    if (tid == 0)
        atomicAdd(total, s_part[0] + s_part[1] + s_part[2] + s_part[3]);
}

extern "C" void kernel_launch(void* const* d_in, const int* in_sizes, int n_in,
                              void* d_out, int out_size, void* d_ws, size_t ws_size,
                              hipStream_t stream) {
    const float* x  = (const float*)d_in[0];   // "input"  [16,3,512,512] fp32
    const float* op = (const float*)d_in[1];   // "output" [16,3,512,512] fp32
    float* total = (float*)d_out;              // scalar fp32

    hipMemsetAsync(total, 0, sizeof(float), stream);

    dim3 grid(WW / TW, HH / TH, BATCH);        // 16 x 64 x 16 = 16384 blocks
    dim3 block(TW, TH);                        // 256 threads
    smooth_loss_kernel<<<grid, block, 0, stream>>>(x, op, total);
}

// Round 2
// 77.575 us; speedup vs baseline: 2.9508x; 2.9508x over previous
//
#include <hip/hip_runtime.h>

#define HH 512
#define WW 512
#define NB 16
#define NTOT (NB * 3 * HH * WW)   // 12582912, divisible by 3 and 4

// 12 unique offsets (each appears twice in the reference's 24-offset list with
// flipped sign; di enters squared and do as |.|, so contributions are equal -> 2x).
// Grouped by dy: dy=0: dx={1,2}; dy=1: dx={-2..2}; dy=2: dx={-2..2}.

__launch_bounds__(256)
__global__ void smooth_loss_kernel(const float* __restrict__ x,
                                   const float* __restrict__ op,
                                   float* __restrict__ total)
{
    // tile: 128 wide x 8 tall, halo: 2 rows below, +/-2 cols (stored at cu = w - (w0-4))
    __shared__ alignas(16) float s_y[3][10][136];
    __shared__ alignas(16) float s_o[3][10][136];
    __shared__ float s_part[4];

    const int b  = blockIdx.z;
    const int h0 = blockIdx.y * 8;
    const int w0 = blockIdx.x * 128;
    const int tx = threadIdx.x;            // 0..31
    const int ty = threadIdx.y;            // 0..7
    const int tid = ty * 32 + tx;

    // ---------- stage output tile: 30 rows x 34 aligned float4 chunks ----------
    for (int t = tid; t < 30 * 34; t += 256) {
        const int rr = t / 34;
        const int k  = t - rr * 34;
        const int c  = rr / 10;
        const int r  = rr - c * 10;
        const int fb = ((b * 3 + c) * HH + (h0 + r)) * WW + (w0 - 4); // cu=0 flat idx
        int f = fb + 4 * k;
        f = min(max(f, 0), NTOT - 4);      // clamp: halo/bottom rows are don't-care
        const float4 v = *(const float4*)(op + f);
        *(float4*)&s_o[c][r][4 * k] = v;
    }

    // ---------- stage ycc tile: 30 rows x up-to-13 group-quad chunks ----------
    // ycc[f] = dot(x[3g..3g+2], mat[:,j]) + bias[j], g=f/3, j=f%3 (faithful to
    // the reference's reshape(-1,3) @ mat). A chunk = 4 groups = 12 floats,
    // base f0 = 12*c4 -> 48-byte (16B-aligned) global offsets.
    for (int t = tid; t < 30 * 13; t += 256) {
        const int rr = t / 13;
        const int k  = t - rr * 13;
        const int c  = rr / 10;
        const int r  = rr - c * 10;
        const int fb = ((b * 3 + c) * HH + (h0 + r)) * WW + (w0 - 4);
        const int qs = (fb + 2) / 3;       // first group needed (covers cu>=2)
        const int qe = (fb + 133) / 3;     // last group needed  (covers cu<=133)
        const int c4 = (qs >> 2) + k;
        if (c4 <= (qe >> 2)) {
            const int f0 = 12 * c4;
            float xv[12];
            *(float4*)&xv[0] = *(const float4*)(x + min(f0,     NTOT - 4));
            *(float4*)&xv[4] = *(const float4*)(x + min(f0 + 4, NTOT - 4));
            *(float4*)&xv[8] = *(const float4*)(x + min(f0 + 8, NTOT - 4));
            float yv[12];
#pragma unroll
            for (int g = 0; g < 4; ++g) {
                const float x0 = xv[3*g], x1 = xv[3*g+1], x2 = xv[3*g+2];
                yv[3*g+0] = fmaf(x0, 0.257f, fmaf(x1, 0.564f, fmaf(x2, 0.098f, 16.f/255.f)));
                yv[3*g+1] = fmaf(x0,-0.148f, fmaf(x1,-0.291f, fmaf(x2, 0.439f, 128.f/255.f)));
                yv[3*g+2] = fmaf(x0, 0.439f, fmaf(x1,-0.368f, fmaf(x2,-0.071f, 128.f/255.f)));
            }
            const int cu0 = f0 - fb;       // multiple of 4 (fb ≡ 0 mod 4)
            if (cu0 >= 0 && cu0 <= 136 - 12) {
                *(float4*)&s_y[c][r][cu0    ] = make_float4(yv[0], yv[1], yv[2],  yv[3]);
                *(float4*)&s_y[c][r][cu0 + 4] = make_float4(yv[4], yv[5], yv[6],  yv[7]);
                *(float4*)&s_y[c][r][cu0 + 8] = make_float4(yv[8], yv[9], yv[10], yv[11]);
            } else {
#pragma unroll
                for (int i = 0; i < 12; ++i) {
                    const int cu = cu0 + i;
                    if (cu >= 0 && cu < 136) s_y[c][r][cu] = yv[i];
                }
            }
        }
    }

    __syncthreads();

    // ---------- compute: each thread owns 4 consecutive pixels in w ----------
    const int h  = h0 + ty;                // always < HH
    const int wq = w0 + 4 * tx;            // first owned col
    // pixel p lives at cu = 4*tx + 4 + p

    float by[3][4], bo[3][4];
#pragma unroll
    for (int c = 0; c < 3; ++c) {
        float4 v = *(const float4*)&s_y[c][ty][4*tx + 4];
        by[c][0] = v.x; by[c][1] = v.y; by[c][2] = v.z; by[c][3] = v.w;
        v = *(const float4*)&s_o[c][ty][4*tx + 4];
        bo[c][0] = v.x; bo[c][1] = v.y; bo[c][2] = v.z; bo[c][3] = v.w;
    }

    float acc = 0.f;

    // ---- dy = 0, dx = 1,2 (same row) ----
    {
        float ey[3][2], eo[3][2];
#pragma unroll
        for (int c = 0; c < 3; ++c) {
            float2 e = *(const float2*)&s_y[c][ty][4*tx + 8];
            ey[c][0] = e.x; ey[c][1] = e.y;
            e = *(const float2*)&s_o[c][ty][4*tx + 8];
            eo[c][0] = e.x; eo[c][1] = e.y;
        }
#pragma unroll
        for (int dx = 1; dx <= 2; ++dx) {
            const float inv = 2.0f / (float)(NB * HH * (WW - dx));
#pragma unroll
            for (int p = 0; p < 4; ++p) {
                const int i = p + dx;      // compile-time after unroll
                const float d0 = ((i < 4) ? by[0][i] : ey[0][i-4]) - by[0][p];
                const float d1 = ((i < 4) ? by[1][i] : ey[1][i-4]) - by[1][p];
                const float d2 = ((i < 4) ? by[2][i] : ey[2][i-4]) - by[2][p];
                const float sad = fabsf(((i < 4) ? bo[0][i] : eo[0][i-4]) - bo[0][p])
                                + fabsf(((i < 4) ? bo[1][i] : eo[1][i-4]) - bo[1][p])
                                + fabsf(((i < 4) ? bo[2][i] : eo[2][i-4]) - bo[2][p]);
                const float sc = (wq + p + dx < WW) ? inv : 0.f;
                acc = fmaf(sc * __expf((-1.f/200.f) * (d0*d0 + d1*d1 + d2*d2)), sad, acc);
            }
        }
    }

    // ---- dy = 1, 2 (rows below; dx = -2..2) ----
#pragma unroll
    for (int dy = 1; dy <= 2; ++dy) {
        const int r = ty + dy;
        float hy[3][12];
#pragma unroll
        for (int c = 0; c < 3; ++c) {
            float4 v = *(const float4*)&s_y[c][r][4*tx];
            hy[c][0] = v.x; hy[c][1] = v.y; hy[c][2]  = v.z; hy[c][3]  = v.w;
            v = *(const float4*)&s_y[c][r][4*tx + 4];
            hy[c][4] = v.x; hy[c][5] = v.y; hy[c][6]  = v.z; hy[c][7]  = v.w;
            v = *(const float4*)&s_y[c][r][4*tx + 8];
            hy[c][8] = v.x; hy[c][9] = v.y; hy[c][10] = v.z; hy[c][11] = v.w;
        }
        float esq[5][4];
#pragma unroll
        for (int dx = -2; dx <= 2; ++dx)
#pragma unroll
            for (int p = 0; p < 4; ++p) {
                const float d0 = hy[0][4 + p + dx] - by[0][p];
                const float d1 = hy[1][4 + p + dx] - by[1][p];
                const float d2 = hy[2][4 + p + dx] - by[2][p];
                esq[dx + 2][p] = d0*d0 + d1*d1 + d2*d2;
            }
        float ho[3][12];
#pragma unroll
        for (int c = 0; c < 3; ++c) {
            float4 v = *(const float4*)&s_o[c][r][4*tx];
            ho[c][0] = v.x; ho[c][1] = v.y; ho[c][2]  = v.z; ho[c][3]  = v.w;
            v = *(const float4*)&s_o[c][r][4*tx + 4];
            ho[c][4] = v.x; ho[c][5] = v.y; ho[c][6]  = v.z; ho[c][7]  = v.w;
            v = *(const float4*)&s_o[c][r][4*tx + 8];
            ho[c][8] = v.x; ho[c][9] = v.y; ho[c][10] = v.z; ho[c][11] = v.w;
        }
        const bool rowOK = (h + dy) < HH;
#pragma unroll
        for (int dx = -2; dx <= 2; ++dx) {
            const int adx = (dx < 0) ? -dx : dx;
            const float inv = 2.0f / (float)(NB * (HH - dy) * (WW - adx));
#pragma unroll
            for (int p = 0; p < 4; ++p) {
                const float sad = fabsf(ho[0][4 + p + dx] - bo[0][p])
                                + fabsf(ho[1][4 + p + dx] - bo[1][p])
                                + fabsf(ho[2][4 + p + dx] - bo[2][p]);
                const int wn = wq + p + dx;
                const float sc = (rowOK && wn >= 0 && wn < WW) ? inv : 0.f;
                acc = fmaf(sc * __expf((-1.f/200.f) * esq[dx + 2][p]), sad, acc);
            }
        }
    }

    // ---------- reduction: wave shuffle -> LDS -> one atomic per block ----------
#pragma unroll
    for (int off = 32; off > 0; off >>= 1)
        acc += __shfl_down(acc, off, 64);

    if ((tid & 63) == 0) s_part[tid >> 6] = acc;
    __syncthreads();
    if (tid == 0)
        atomicAdd(total, s_part[0] + s_part[1] + s_part[2] + s_part[3]);
}

extern "C" void kernel_launch(void* const* d_in, const int* in_sizes, int n_in,
                              void* d_out, int out_size, void* d_ws, size_t ws_size,
                              hipStream_t stream) {
    const float* x  = (const float*)d_in[0];   // "input"  [16,3,512,512] fp32
    const float* op = (const float*)d_in[1];   // "output" [16,3,512,512] fp32
    float* total = (float*)d_out;              // scalar fp32

    hipMemsetAsync(total, 0, sizeof(float), stream);

    dim3 grid(WW / 128, HH / 8, NB);           // 4 x 64 x 16 = 4096 blocks
    dim3 block(32, 8);                         // 256 threads, 4 px/thread
    smooth_loss_kernel<<<grid, block, 0, stream>>>(x, op, total);
}